// Round 5
// baseline (248.095 us; speedup 1.0000x reference)
//
#include <hip/hip_runtime.h>
#include <stdint.h>

#define BN 4096
#define DD 128
#define EPSF 1e-6f
#define MARGINF 1.0f
#define TM 128
#define TN 128

typedef unsigned long long ull;
typedef unsigned short ushort;
typedef short short8 __attribute__((ext_vector_type(8)));
typedef float f32x4 __attribute__((ext_vector_type(4)));

__device__ __forceinline__ unsigned int ord_f32(float f) {
    unsigned int u = __float_as_uint(f);
    return (u & 0x80000000u) ? ~u : (u | 0x80000000u);
}
__device__ __forceinline__ ushort bf16_rne(float x) {
    unsigned int u = __float_as_uint(x);
    return (ushort)((u + 0x7FFFu + ((u >> 16) & 1u)) >> 16);
}

// --- prep: row stats + inv perm + key init + bf16 hi/lo split of e ---
__global__ void k_prep(const float* __restrict__ e, const int* __restrict__ tidx,
                       float* __restrict__ sq, float* __restrict__ s,
                       int* __restrict__ inv, ull* __restrict__ pk, ull* __restrict__ nk,
                       unsigned int* __restrict__ ehi, unsigned int* __restrict__ elo) {
    int w = threadIdx.x >> 6, lane = threadIdx.x & 63;
    int row = blockIdx.x * 4 + w;
    float2 v = ((const float2*)(e + (size_t)row * DD))[lane];
    ushort hx = bf16_rne(v.x), hy = bf16_rne(v.y);
    float rx = v.x - __uint_as_float((unsigned int)hx << 16);
    float ry = v.y - __uint_as_float((unsigned int)hy << 16);
    ushort lx = bf16_rne(rx), ly = bf16_rne(ry);
    ehi[row * 64 + lane] = (unsigned int)hx | ((unsigned int)hy << 16);
    elo[row * 64 + lane] = (unsigned int)lx | ((unsigned int)ly << 16);
    float ss = v.x + v.y;
    float qq = v.x * v.x + v.y * v.y;
    #pragma unroll
    for (int off = 32; off > 0; off >>= 1) {
        ss += __shfl_down(ss, off);
        qq += __shfl_down(qq, off);
    }
    if (lane == 0) {
        sq[row] = qq; s[row] = ss;
        inv[tidx[row]] = row;
        pk[row] = 0ULL; nk[row] = ~0ULL;
    }
}

// --- compress masks to bitmaps: thread = 16 consecutive cols, no ballot ---
// bit layout identical to ull[64]-per-row little-endian (bit = col%64 of word col/64)
__global__ void k_bits(const int* __restrict__ pos, const int* __restrict__ neg,
                       ushort* __restrict__ pb, ushort* __restrict__ nb) {
    const int row = blockIdx.x, t = threadIdx.x;
    const int4* pr = (const int4*)(pos + (size_t)row * BN) + t * 4;
    const int4* nr = (const int4*)(neg + (size_t)row * BN) + t * 4;
    int4 p0 = pr[0], p1 = pr[1], p2 = pr[2], p3 = pr[3];
    int4 n0 = nr[0], n1 = nr[1], n2 = nr[2], n3 = nr[3];
    unsigned int m = 0;
    m |= (p0.x != 0) << 0;  m |= (p0.y != 0) << 1;  m |= (p0.z != 0) << 2;  m |= (p0.w != 0) << 3;
    m |= (p1.x != 0) << 4;  m |= (p1.y != 0) << 5;  m |= (p1.z != 0) << 6;  m |= (p1.w != 0) << 7;
    m |= (p2.x != 0) << 8;  m |= (p2.y != 0) << 9;  m |= (p2.z != 0) << 10; m |= (p2.w != 0) << 11;
    m |= (p3.x != 0) << 12; m |= (p3.y != 0) << 13; m |= (p3.z != 0) << 14; m |= (p3.w != 0) << 15;
    pb[(size_t)row * 256 + t] = (ushort)m;
    m = 0;
    m |= (n0.x != 0) << 0;  m |= (n0.y != 0) << 1;  m |= (n0.z != 0) << 2;  m |= (n0.w != 0) << 3;
    m |= (n1.x != 0) << 4;  m |= (n1.y != 0) << 5;  m |= (n1.z != 0) << 6;  m |= (n1.w != 0) << 7;
    m |= (n2.x != 0) << 8;  m |= (n2.y != 0) << 9;  m |= (n2.z != 0) << 10; m |= (n2.w != 0) << 11;
    m |= (n3.x != 0) << 12; m |= (n3.y != 0) << 13; m |= (n3.z != 0) << 14; m |= (n3.w != 0) << 15;
    nb[(size_t)row * 256 + t] = (ushort)m;
}

// --- MFMA split-bf16 d^2 + selection directly in C-layout registers ---
// No LDS staging: A/B fragments loaded straight from global (L2/L3-resident).
__global__ __launch_bounds__(256, 3)
void k_select(const ushort* __restrict__ ehi, const ushort* __restrict__ elo,
              const float* __restrict__ sq, const float* __restrict__ s,
              const int* __restrict__ inv,
              const ull* __restrict__ pbits, const ull* __restrict__ nbits,
              ull* __restrict__ pkey, ull* __restrict__ nkey) {
    __shared__ float spv[2048]; __shared__ int spi[2048];
    __shared__ float snv[2048]; __shared__ int sni[2048];   // 32 KB merge scratch
    __shared__ ull pbl[256], nbl[256];                      // 4 KB bitmap tile

    const int tid = threadIdx.x;
    const int lane = tid & 63, w = tid >> 6;
    const int lrow = lane & 15, quad = lane >> 4;
    const int i0 = blockIdx.x * TM, c0 = blockIdx.y * TN;

    // bitmap tile (cooperative, coalesced)
    {
        int irow = tid >> 1, half = tid & 1;
        size_t b = (size_t)(i0 + irow) * 64 + (c0 >> 6) + half;
        pbl[tid] = pbits[b];
        nbl[tid] = nbits[b];
    }

    // per-lane j columns + row terms (registers, no LDS)
    int jreg[8]; float rjv[8];
    #pragma unroll
    for (int ct = 0; ct < 8; ct++) {
        int j = inv[c0 + ct * 16 + lrow];
        jreg[ct] = j;
        rjv[ct] = sq[j] - 2.0f * EPSF * s[j];
    }
    float riv[8];
    #pragma unroll
    for (int rt = 0; rt < 2; rt++)
        #pragma unroll
        for (int t = 0; t < 4; t++) {
            int row = i0 + w * 32 + rt * 16 + quad * 4 + t;
            riv[rt * 4 + t] = sq[row] + 2.0f * EPSF * s[row];
        }

    __syncthreads();   // bitmap visible

    f32x4 acc[2][8];
    #pragma unroll
    for (int rt = 0; rt < 2; rt++)
        #pragma unroll
        for (int ct = 0; ct < 8; ct++)
            acc[rt][ct] = (f32x4){0.f, 0.f, 0.f, 0.f};

    // K-loop: fragments direct from global; no barriers, no vmcnt drains
    #pragma unroll
    for (int kk = 0; kk < 4; kk++) {
        const int kof = kk * 32 + quad * 8;
        short8 ah[2], al[2];
        #pragma unroll
        for (int rt = 0; rt < 2; rt++) {
            size_t off = (size_t)(i0 + w * 32 + rt * 16 + lrow) * DD + kof;
            ah[rt] = *(const short8*)(ehi + off);
            al[rt] = *(const short8*)(elo + off);
        }
        #pragma unroll
        for (int ct = 0; ct < 8; ct++) {
            size_t off = (size_t)jreg[ct] * DD + kof;
            short8 bh = *(const short8*)(ehi + off);
            short8 bl = *(const short8*)(elo + off);
            #pragma unroll
            for (int rt = 0; rt < 2; rt++) {
                acc[rt][ct] = __builtin_amdgcn_mfma_f32_16x16x32_bf16(ah[rt], bh, acc[rt][ct], 0, 0, 0);
                acc[rt][ct] = __builtin_amdgcn_mfma_f32_16x16x32_bf16(ah[rt], bl, acc[rt][ct], 0, 0, 0);
                acc[rt][ct] = __builtin_amdgcn_mfma_f32_16x16x32_bf16(al[rt], bh, acc[rt][ct], 0, 0, 0);
            }
        }
    }

    // selection in C-layout: lane holds rows w*32+rt*16+quad*4+t, cols ct*16+lrow
    float bpv[8], bnv[8]; int bpi[8], bni[8];
    #pragma unroll
    for (int r = 0; r < 8; r++) {
        bpv[r] = -3.4e38f; bnv[r] = 3.4e38f;
        bpi[r] = 0x7FFFFFFF; bni[r] = 0x7FFFFFFF;
    }
    #pragma unroll
    for (int rt = 0; rt < 2; rt++)
        #pragma unroll
        for (int t = 0; t < 4; t++) {
            const int r = rt * 4 + t;
            const int row = w * 32 + rt * 16 + quad * 4 + t;
            ull p0 = pbl[row * 2] >> lrow, p1 = pbl[row * 2 + 1] >> lrow;
            ull n0 = nbl[row * 2] >> lrow, n1 = nbl[row * 2 + 1] >> lrow;
            float rv = riv[r];
            #pragma unroll
            for (int ct = 0; ct < 8; ct++) {
                float d2 = rv + rjv[ct] - 2.0f * acc[rt][ct][t] + (float)DD * EPSF * EPSF;
                int j = jreg[ct];
                int sh = (ct & 3) * 16;
                ull pw = (ct < 4) ? p0 : p1;
                ull nw = (ct < 4) ? n0 : n1;
                if ((pw >> sh) & 1ULL) {
                    if (d2 > bpv[r] || (d2 == bpv[r] && j < bpi[r])) { bpv[r] = d2; bpi[r] = j; }
                }
                if ((nw >> sh) & 1ULL) {
                    if (d2 < bnv[r] || (d2 == bnv[r] && j < bni[r])) { bnv[r] = d2; bni[r] = j; }
                }
            }
        }

    // scratch: 16 lanes (lrow) per row -> merge
    #pragma unroll
    for (int rt = 0; rt < 2; rt++)
        #pragma unroll
        for (int t = 0; t < 4; t++) {
            const int r = rt * 4 + t;
            const int row = w * 32 + rt * 16 + quad * 4 + t;
            spv[row * 16 + lrow] = bpv[r]; spi[row * 16 + lrow] = bpi[r];
            snv[row * 16 + lrow] = bnv[r]; sni[row * 16 + lrow] = bni[r];
        }
    __syncthreads();
    if (tid < TM) {
        float bv = -3.4e38f, nv = 3.4e38f;
        int bi = 0x7FFFFFFF, ni = 0x7FFFFFFF;
        for (int t = 0; t < 16; t++) {
            float v = spv[tid * 16 + t]; int ix = spi[tid * 16 + t];
            if (ix != 0x7FFFFFFF && (v > bv || (v == bv && ix < bi))) { bv = v; bi = ix; }
            v = snv[tid * 16 + t]; ix = sni[tid * 16 + t];
            if (ix != 0x7FFFFFFF && (v < nv || (v == nv && ix < ni))) { nv = v; ni = ix; }
        }
        if (bi != 0x7FFFFFFF) {
            ull key = ((ull)ord_f32(bv) << 32) | (ull)(0xFFFFFFFFu - (unsigned)bi);
            atomicMax(&pkey[i0 + tid], key);
        }
        if (ni != 0x7FFFFFFF) {
            ull key = ((ull)ord_f32(nv) << 32) | (ull)(unsigned)ni;
            atomicMin(&nkey[i0 + tid], key);
        }
    }
}

// --- per-row triplet loss: wave per row (coalesced), block partials ---
__global__ void k_loss(const float* __restrict__ e,
                       const ull* __restrict__ pkey, const ull* __restrict__ nkey,
                       float* __restrict__ partials) {
    int w = threadIdx.x >> 6, lane = threadIdx.x & 63;
    int row = blockIdx.x * 4 + w;
    ull pk = pkey[row], nk = nkey[row];
    float loss = 0.0f, wt = 0.0f;
    if (pk != 0ULL && nk != ~0ULL) {
        int pi = (int)(0xFFFFFFFFu - (unsigned)(pk & 0xFFFFFFFFu));
        int ni = (int)(unsigned)(nk & 0xFFFFFFFFu);
        float2 av = ((const float2*)(e + (size_t)row * DD))[lane];
        float2 pv = ((const float2*)(e + (size_t)pi * DD))[lane];
        float2 nv = ((const float2*)(e + (size_t)ni * DD))[lane];
        float dx, dy;
        dx = av.x - pv.x + EPSF; dy = av.y - pv.y + EPSF;
        float ap2 = dx * dx + dy * dy;
        dx = av.x - nv.x + EPSF; dy = av.y - nv.y + EPSF;
        float an2 = dx * dx + dy * dy;
        dx = pv.x - nv.x + EPSF; dy = pv.y - nv.y + EPSF;
        float pn2 = dx * dx + dy * dy;
        #pragma unroll
        for (int off = 32; off > 0; off >>= 1) {
            ap2 += __shfl_down(ap2, off);
            an2 += __shfl_down(an2, off);
            pn2 += __shfl_down(pn2, off);
        }
        if (lane == 0) {
            float ap = sqrtf(ap2), an = sqrtf(an2), pn = sqrtf(pn2);
            loss = fmaxf(ap - fminf(an, pn) + MARGINF, 0.0f);
            wt = 1.0f;
        }
    }
    __shared__ float sl[4], sw[4];
    if (lane == 0) { sl[w] = loss; sw[w] = wt; }
    __syncthreads();
    if (threadIdx.x == 0) {
        partials[blockIdx.x * 2 + 0] = sl[0] + sl[1] + sl[2] + sl[3];
        partials[blockIdx.x * 2 + 1] = sw[0] + sw[1] + sw[2] + sw[3];
    }
}

// --- finalize ---
__global__ void k_final(const float* __restrict__ partials, float* __restrict__ out) {
    int tid = threadIdx.x;
    float L = 0.0f, W = 0.0f;
    for (int i = 0; i < 4; i++) {
        int idx = tid + i * 256;
        L += partials[idx * 2];
        W += partials[idx * 2 + 1];
    }
    #pragma unroll
    for (int off = 32; off > 0; off >>= 1) {
        L += __shfl_down(L, off);
        W += __shfl_down(W, off);
    }
    __shared__ float sl[4], sw[4];
    int w = tid >> 6, lane = tid & 63;
    if (lane == 0) { sl[w] = L; sw[w] = W; }
    __syncthreads();
    if (tid == 0) {
        float Lt = sl[0] + sl[1] + sl[2] + sl[3];
        float Wt = sw[0] + sw[1] + sw[2] + sw[3];
        out[0] = Lt / fmaxf(Wt, 1.0f);
    }
}

extern "C" void kernel_launch(void* const* d_in, const int* in_sizes, int n_in,
                              void* d_out, int out_size, void* d_ws, size_t ws_size,
                              hipStream_t stream) {
    const float* e    = (const float*)d_in[0];
    const int*   tidx = (const int*)d_in[1];
    const int*   pos  = (const int*)d_in[2];
    const int*   neg  = (const int*)d_in[3];
    float* out = (float*)d_out;

    ull* pkey  = (ull*)d_ws;                  // 4096
    ull* nkey  = pkey + BN;                   // 4096
    ull* pbits = nkey + BN;                   // 4096*64
    ull* nbits = pbits + BN * 64;             // 4096*64
    float* sq  = (float*)(nbits + BN * 64);
    float* s   = sq + BN;
    int* inv   = (int*)(s + BN);
    float* partials = (float*)(inv + BN);     // 2048
    unsigned int* ehi = (unsigned int*)(partials + 2048);  // 4096*64 uints
    unsigned int* elo = ehi + BN * 64;

    k_prep<<<BN / 4, 256, 0, stream>>>(e, tidx, sq, s, inv, pkey, nkey, ehi, elo);
    k_bits<<<BN, 256, 0, stream>>>(pos, neg, (ushort*)pbits, (ushort*)nbits);
    dim3 grid(BN / TM, BN / TN);
    k_select<<<grid, 256, 0, stream>>>((const ushort*)ehi, (const ushort*)elo,
                                       sq, s, inv, pbits, nbits, pkey, nkey);
    k_loss<<<BN / 4, 256, 0, stream>>>(e, pkey, nkey, partials);
    k_final<<<1, 256, 0, stream>>>(partials, out);
}

// Round 6
// 206.350 us; speedup vs baseline: 1.2023x; 1.2023x over previous
//
#include <hip/hip_runtime.h>
#include <stdint.h>

#define BN 4096
#define DD 128
#define EPSF 1e-6f
#define MARGINF 1.0f
#define TT 64      // tile: 64x64

typedef unsigned long long ull;
typedef unsigned short ushort;
typedef short short8 __attribute__((ext_vector_type(8)));
typedef float f32x4 __attribute__((ext_vector_type(4)));

__device__ __forceinline__ unsigned int ord_f32(float f) {
    unsigned int u = __float_as_uint(f);
    return (u & 0x80000000u) ? ~u : (u | 0x80000000u);
}
__device__ __forceinline__ ushort bf16_rne(float x) {
    unsigned int u = __float_as_uint(x);
    return (ushort)((u + 0x7FFFu + ((u >> 16) & 1u)) >> 16);
}

// --- prep: row stats + inv perm + key init + bf16 hi/lo split of e ---
__global__ void k_prep(const float* __restrict__ e, const int* __restrict__ tidx,
                       float* __restrict__ sq, float* __restrict__ s,
                       int* __restrict__ inv, ull* __restrict__ pk, ull* __restrict__ nk,
                       unsigned int* __restrict__ ehi, unsigned int* __restrict__ elo) {
    int w = threadIdx.x >> 6, lane = threadIdx.x & 63;
    int row = blockIdx.x * 4 + w;
    float2 v = ((const float2*)(e + (size_t)row * DD))[lane];
    ushort hx = bf16_rne(v.x), hy = bf16_rne(v.y);
    float rx = v.x - __uint_as_float((unsigned int)hx << 16);
    float ry = v.y - __uint_as_float((unsigned int)hy << 16);
    ushort lx = bf16_rne(rx), ly = bf16_rne(ry);
    ehi[row * 64 + lane] = (unsigned int)hx | ((unsigned int)hy << 16);
    elo[row * 64 + lane] = (unsigned int)lx | ((unsigned int)ly << 16);
    float ss = v.x + v.y;
    float qq = v.x * v.x + v.y * v.y;
    #pragma unroll
    for (int off = 32; off > 0; off >>= 1) {
        ss += __shfl_down(ss, off);
        qq += __shfl_down(qq, off);
    }
    if (lane == 0) {
        sq[row] = qq; s[row] = ss;
        inv[tidx[row]] = row;
        pk[row] = 0ULL; nk[row] = ~0ULL;
    }
}

// --- compress masks to bitmaps: thread = 16 consecutive cols, no ballot ---
__global__ void k_bits(const int* __restrict__ pos, const int* __restrict__ neg,
                       ushort* __restrict__ pb, ushort* __restrict__ nb) {
    const int row = blockIdx.x, t = threadIdx.x;
    const int4* pr = (const int4*)(pos + (size_t)row * BN) + t * 4;
    const int4* nr = (const int4*)(neg + (size_t)row * BN) + t * 4;
    int4 p0 = pr[0], p1 = pr[1], p2 = pr[2], p3 = pr[3];
    int4 n0 = nr[0], n1 = nr[1], n2 = nr[2], n3 = nr[3];
    unsigned int m = 0;
    m |= (p0.x != 0) << 0;  m |= (p0.y != 0) << 1;  m |= (p0.z != 0) << 2;  m |= (p0.w != 0) << 3;
    m |= (p1.x != 0) << 4;  m |= (p1.y != 0) << 5;  m |= (p1.z != 0) << 6;  m |= (p1.w != 0) << 7;
    m |= (p2.x != 0) << 8;  m |= (p2.y != 0) << 9;  m |= (p2.z != 0) << 10; m |= (p2.w != 0) << 11;
    m |= (p3.x != 0) << 12; m |= (p3.y != 0) << 13; m |= (p3.z != 0) << 14; m |= (p3.w != 0) << 15;
    pb[(size_t)row * 256 + t] = (ushort)m;
    m = 0;
    m |= (n0.x != 0) << 0;  m |= (n0.y != 0) << 1;  m |= (n0.z != 0) << 2;  m |= (n0.w != 0) << 3;
    m |= (n1.x != 0) << 4;  m |= (n1.y != 0) << 5;  m |= (n1.z != 0) << 6;  m |= (n1.w != 0) << 7;
    m |= (n2.x != 0) << 8;  m |= (n2.y != 0) << 9;  m |= (n2.z != 0) << 10; m |= (n2.w != 0) << 11;
    m |= (n3.x != 0) << 12; m |= (n3.y != 0) << 13; m |= (n3.z != 0) << 14; m |= (n3.w != 0) << 15;
    nb[(size_t)row * 256 + t] = (ushort)m;
}

// --- MFMA split-bf16 d^2 + selection in C-layout regs; 64x64 tile, 4 blocks/CU ---
__global__ __launch_bounds__(256, 4)
void k_select(const ushort* __restrict__ ehi, const ushort* __restrict__ elo,
              const float* __restrict__ sq, const float* __restrict__ s,
              const int* __restrict__ inv,
              const ull* __restrict__ pbits, const ull* __restrict__ nbits,
              ull* __restrict__ pkey, ull* __restrict__ nkey) {
    // staging: 4 buffers [64 rows][64+8 pad ushorts] = 9216 B each = 36 KB total
    __shared__ __align__(16) ushort stg[4][TT][72];
    __shared__ ull pbl[TT], nbl[TT];          // 1 KB bitmap tile (64 bits per row)
    __shared__ int jvs[TT];
    __shared__ float rjl[TT], ril[TT];

    ushort (*Ah)[72] = stg[0];
    ushort (*Al)[72] = stg[1];
    ushort (*Bh)[72] = stg[2];
    ushort (*Bl)[72] = stg[3];

    const int tid = threadIdx.x;
    const int lane = tid & 63, w = tid >> 6;
    const int lrow = lane & 15, quad = lane >> 4;
    const int i0 = blockIdx.x * TT, c0 = blockIdx.y * TT;

    if (tid < TT) {
        int j = inv[c0 + tid];
        jvs[tid] = j;
        rjl[tid] = sq[j] - 2.0f * EPSF * s[j];
        ril[tid] = sq[i0 + tid] + 2.0f * EPSF * s[i0 + tid];
        pbl[tid] = pbits[(size_t)(i0 + tid) * 64 + (c0 >> 6)];
        nbl[tid] = nbits[(size_t)(i0 + tid) * 64 + (c0 >> 6)];
    }
    __syncthreads();   // jvs visible to staging

    f32x4 acc[4];
    #pragma unroll
    for (int ct = 0; ct < 4; ct++) acc[ct] = (f32x4){0.f, 0.f, 0.f, 0.f};

    const int rr0 = tid >> 3, seg = tid & 7;
    for (int kc = 0; kc < 2; kc++) {
        if (kc) __syncthreads();   // prior compute done before overwrite
        #pragma unroll
        for (int p = 0; p < 2; p++) {
            int rr = p * 32 + rr0;
            int ar = i0 + rr, jr = jvs[rr];
            int4 v;
            v = ((const int4*)ehi)[(size_t)ar * 16 + kc * 8 + seg];
            *(int4*)&Ah[rr][seg * 8] = v;
            v = ((const int4*)elo)[(size_t)ar * 16 + kc * 8 + seg];
            *(int4*)&Al[rr][seg * 8] = v;
            v = ((const int4*)ehi)[(size_t)jr * 16 + kc * 8 + seg];
            *(int4*)&Bh[rr][seg * 8] = v;
            v = ((const int4*)elo)[(size_t)jr * 16 + kc * 8 + seg];
            *(int4*)&Bl[rr][seg * 8] = v;
        }
        __syncthreads();

        #pragma unroll
        for (int ks = 0; ks < 2; ks++) {
            const int kof = ks * 32 + quad * 8;
            short8 ah = *(const short8*)&Ah[w * 16 + lrow][kof];
            short8 al = *(const short8*)&Al[w * 16 + lrow][kof];
            #pragma unroll
            for (int ct = 0; ct < 4; ct++) {
                short8 bh = *(const short8*)&Bh[ct * 16 + lrow][kof];
                short8 bl = *(const short8*)&Bl[ct * 16 + lrow][kof];
                acc[ct] = __builtin_amdgcn_mfma_f32_16x16x32_bf16(ah, bh, acc[ct], 0, 0, 0);
                acc[ct] = __builtin_amdgcn_mfma_f32_16x16x32_bf16(ah, bl, acc[ct], 0, 0, 0);
                acc[ct] = __builtin_amdgcn_mfma_f32_16x16x32_bf16(al, bh, acc[ct], 0, 0, 0);
            }
        }
    }

    // selection in C-layout: lane holds rows w*16+quad*4+t, cols ct*16+lrow
    int jreg[4]; float rjv[4];
    #pragma unroll
    for (int ct = 0; ct < 4; ct++) {
        jreg[ct] = jvs[ct * 16 + lrow];
        rjv[ct] = rjl[ct * 16 + lrow];
    }
    float bpv[4], bnv[4]; int bpi[4], bni[4];
    #pragma unroll
    for (int t = 0; t < 4; t++) {
        const int row = w * 16 + quad * 4 + t;
        ull pb = pbl[row] >> lrow;
        ull nb = nbl[row] >> lrow;
        float rv = ril[row];
        float bv = -3.4e38f, nv = 3.4e38f;
        int bi = 0x7FFFFFFF, ni = 0x7FFFFFFF;
        #pragma unroll
        for (int ct = 0; ct < 4; ct++) {
            float d2 = rv + rjv[ct] - 2.0f * acc[ct][t] + (float)DD * EPSF * EPSF;
            int j = jreg[ct];
            if ((pb >> (ct * 16)) & 1ULL) {
                if (d2 > bv || (d2 == bv && j < bi)) { bv = d2; bi = j; }
            }
            if ((nb >> (ct * 16)) & 1ULL) {
                if (d2 < nv || (d2 == nv && j < ni)) { nv = d2; ni = j; }
            }
        }
        bpv[t] = bv; bpi[t] = bi; bnv[t] = nv; bni[t] = ni;
    }

    // cross-lrow merge via scratch aliased over staging buffers
    __syncthreads();   // all frag reads done
    float* spv = (float*)stg;                 // 64*16 floats
    int*   spi = (int*)(spv + 1024);
    float* snv = (float*)(spi + 1024);
    int*   sni = (int*)(snv + 1024);          // 16 KB total < 36 KB
    #pragma unroll
    for (int t = 0; t < 4; t++) {
        const int row = w * 16 + quad * 4 + t;
        spv[row * 16 + lrow] = bpv[t]; spi[row * 16 + lrow] = bpi[t];
        snv[row * 16 + lrow] = bnv[t]; sni[row * 16 + lrow] = bni[t];
    }
    __syncthreads();
    if (tid < TT) {
        float bv = -3.4e38f, nv = 3.4e38f;
        int bi = 0x7FFFFFFF, ni = 0x7FFFFFFF;
        for (int t = 0; t < 16; t++) {
            float v = spv[tid * 16 + t]; int ix = spi[tid * 16 + t];
            if (ix != 0x7FFFFFFF && (v > bv || (v == bv && ix < bi))) { bv = v; bi = ix; }
            v = snv[tid * 16 + t]; ix = sni[tid * 16 + t];
            if (ix != 0x7FFFFFFF && (v < nv || (v == nv && ix < ni))) { nv = v; ni = ix; }
        }
        if (bi != 0x7FFFFFFF) {
            ull key = ((ull)ord_f32(bv) << 32) | (ull)(0xFFFFFFFFu - (unsigned)bi);
            atomicMax(&pkey[i0 + tid], key);
        }
        if (ni != 0x7FFFFFFF) {
            ull key = ((ull)ord_f32(nv) << 32) | (ull)(unsigned)ni;
            atomicMin(&nkey[i0 + tid], key);
        }
    }
}

// --- per-row triplet loss: wave per row (coalesced), block partials ---
__global__ void k_loss(const float* __restrict__ e,
                       const ull* __restrict__ pkey, const ull* __restrict__ nkey,
                       float* __restrict__ partials) {
    int w = threadIdx.x >> 6, lane = threadIdx.x & 63;
    int row = blockIdx.x * 4 + w;
    ull pk = pkey[row], nk = nkey[row];
    float loss = 0.0f, wt = 0.0f;
    if (pk != 0ULL && nk != ~0ULL) {
        int pi = (int)(0xFFFFFFFFu - (unsigned)(pk & 0xFFFFFFFFu));
        int ni = (int)(unsigned)(nk & 0xFFFFFFFFu);
        float2 av = ((const float2*)(e + (size_t)row * DD))[lane];
        float2 pv = ((const float2*)(e + (size_t)pi * DD))[lane];
        float2 nv = ((const float2*)(e + (size_t)ni * DD))[lane];
        float dx, dy;
        dx = av.x - pv.x + EPSF; dy = av.y - pv.y + EPSF;
        float ap2 = dx * dx + dy * dy;
        dx = av.x - nv.x + EPSF; dy = av.y - nv.y + EPSF;
        float an2 = dx * dx + dy * dy;
        dx = pv.x - nv.x + EPSF; dy = pv.y - nv.y + EPSF;
        float pn2 = dx * dx + dy * dy;
        #pragma unroll
        for (int off = 32; off > 0; off >>= 1) {
            ap2 += __shfl_down(ap2, off);
            an2 += __shfl_down(an2, off);
            pn2 += __shfl_down(pn2, off);
        }
        if (lane == 0) {
            float ap = sqrtf(ap2), an = sqrtf(an2), pn = sqrtf(pn2);
            loss = fmaxf(ap - fminf(an, pn) + MARGINF, 0.0f);
            wt = 1.0f;
        }
    }
    __shared__ float sl[4], sw[4];
    if (lane == 0) { sl[w] = loss; sw[w] = wt; }
    __syncthreads();
    if (threadIdx.x == 0) {
        partials[blockIdx.x * 2 + 0] = sl[0] + sl[1] + sl[2] + sl[3];
        partials[blockIdx.x * 2 + 1] = sw[0] + sw[1] + sw[2] + sw[3];
    }
}

// --- finalize ---
__global__ void k_final(const float* __restrict__ partials, float* __restrict__ out) {
    int tid = threadIdx.x;
    float L = 0.0f, W = 0.0f;
    for (int i = 0; i < 4; i++) {
        int idx = tid + i * 256;
        L += partials[idx * 2];
        W += partials[idx * 2 + 1];
    }
    #pragma unroll
    for (int off = 32; off > 0; off >>= 1) {
        L += __shfl_down(L, off);
        W += __shfl_down(W, off);
    }
    __shared__ float sl[4], sw[4];
    int w = tid >> 6, lane = tid & 63;
    if (lane == 0) { sl[w] = L; sw[w] = W; }
    __syncthreads();
    if (tid == 0) {
        float Lt = sl[0] + sl[1] + sl[2] + sl[3];
        float Wt = sw[0] + sw[1] + sw[2] + sw[3];
        out[0] = Lt / fmaxf(Wt, 1.0f);
    }
}

extern "C" void kernel_launch(void* const* d_in, const int* in_sizes, int n_in,
                              void* d_out, int out_size, void* d_ws, size_t ws_size,
                              hipStream_t stream) {
    const float* e    = (const float*)d_in[0];
    const int*   tidx = (const int*)d_in[1];
    const int*   pos  = (const int*)d_in[2];
    const int*   neg  = (const int*)d_in[3];
    float* out = (float*)d_out;

    ull* pkey  = (ull*)d_ws;                  // 4096
    ull* nkey  = pkey + BN;                   // 4096
    ull* pbits = nkey + BN;                   // 4096*64
    ull* nbits = pbits + BN * 64;             // 4096*64
    float* sq  = (float*)(nbits + BN * 64);
    float* s   = sq + BN;
    int* inv   = (int*)(s + BN);
    float* partials = (float*)(inv + BN);     // 2048
    unsigned int* ehi = (unsigned int*)(partials + 2048);  // 4096*64 uints
    unsigned int* elo = ehi + BN * 64;

    k_prep<<<BN / 4, 256, 0, stream>>>(e, tidx, sq, s, inv, pkey, nkey, ehi, elo);
    k_bits<<<BN, 256, 0, stream>>>(pos, neg, (ushort*)pbits, (ushort*)nbits);
    dim3 grid(BN / TT, BN / TT);
    k_select<<<grid, 256, 0, stream>>>((const ushort*)ehi, (const ushort*)elo,
                                       sq, s, inv, pbits, nbits, pkey, nkey);
    k_loss<<<BN / 4, 256, 0, stream>>>(e, pkey, nkey, partials);
    k_final<<<1, 256, 0, stream>>>(partials, out);
}

// Round 7
// 203.218 us; speedup vs baseline: 1.2208x; 1.0154x over previous
//
#include <hip/hip_runtime.h>
#include <stdint.h>

#define BN 4096
#define DD 128
#define EPSF 1e-6f
#define MARGINF 1.0f

typedef unsigned long long ull;
typedef unsigned short ushort;
typedef short short8 __attribute__((ext_vector_type(8)));
typedef float f32x4 __attribute__((ext_vector_type(4)));

__device__ __forceinline__ unsigned int ord_f32(float f) {
    unsigned int u = __float_as_uint(f);
    return (u & 0x80000000u) ? ~u : (u | 0x80000000u);
}
__device__ __forceinline__ ushort bf16_rne(float x) {
    unsigned int u = __float_as_uint(x);
    return (ushort)((u + 0x7FFFu + ((u >> 16) & 1u)) >> 16);
}

// --- prep: row stats + inv perm + key init + bf16 hi/lo split of e ---
__global__ void k_prep(const float* __restrict__ e, const int* __restrict__ tidx,
                       float* __restrict__ sq, float* __restrict__ s,
                       int* __restrict__ inv, ull* __restrict__ pk, ull* __restrict__ nk,
                       unsigned int* __restrict__ ehi, unsigned int* __restrict__ elo) {
    int w = threadIdx.x >> 6, lane = threadIdx.x & 63;
    int row = blockIdx.x * 4 + w;
    float2 v = ((const float2*)(e + (size_t)row * DD))[lane];
    ushort hx = bf16_rne(v.x), hy = bf16_rne(v.y);
    float rx = v.x - __uint_as_float((unsigned int)hx << 16);
    float ry = v.y - __uint_as_float((unsigned int)hy << 16);
    ushort lx = bf16_rne(rx), ly = bf16_rne(ry);
    ehi[row * 64 + lane] = (unsigned int)hx | ((unsigned int)hy << 16);
    elo[row * 64 + lane] = (unsigned int)lx | ((unsigned int)ly << 16);
    float ss = v.x + v.y;
    float qq = v.x * v.x + v.y * v.y;
    #pragma unroll
    for (int off = 32; off > 0; off >>= 1) {
        ss += __shfl_down(ss, off);
        qq += __shfl_down(qq, off);
    }
    if (lane == 0) {
        sq[row] = qq; s[row] = ss;
        inv[tidx[row]] = row;
        pk[row] = 0ULL; nk[row] = 0ULL;   // both max-merged now (neg uses inverted keys)
    }
}

// --- compress masks to bitmaps: thread = 16 consecutive cols, no ballot ---
__global__ void k_bits(const int* __restrict__ pos, const int* __restrict__ neg,
                       ushort* __restrict__ pb, ushort* __restrict__ nb) {
    const int row = blockIdx.x, t = threadIdx.x;
    const int4* pr = (const int4*)(pos + (size_t)row * BN) + t * 4;
    const int4* nr = (const int4*)(neg + (size_t)row * BN) + t * 4;
    int4 p0 = pr[0], p1 = pr[1], p2 = pr[2], p3 = pr[3];
    int4 n0 = nr[0], n1 = nr[1], n2 = nr[2], n3 = nr[3];
    unsigned int m = 0;
    m |= (p0.x != 0) << 0;  m |= (p0.y != 0) << 1;  m |= (p0.z != 0) << 2;  m |= (p0.w != 0) << 3;
    m |= (p1.x != 0) << 4;  m |= (p1.y != 0) << 5;  m |= (p1.z != 0) << 6;  m |= (p1.w != 0) << 7;
    m |= (p2.x != 0) << 8;  m |= (p2.y != 0) << 9;  m |= (p2.z != 0) << 10; m |= (p2.w != 0) << 11;
    m |= (p3.x != 0) << 12; m |= (p3.y != 0) << 13; m |= (p3.z != 0) << 14; m |= (p3.w != 0) << 15;
    pb[(size_t)row * 256 + t] = (ushort)m;
    m = 0;
    m |= (n0.x != 0) << 0;  m |= (n0.y != 0) << 1;  m |= (n0.z != 0) << 2;  m |= (n0.w != 0) << 3;
    m |= (n1.x != 0) << 4;  m |= (n1.y != 0) << 5;  m |= (n1.z != 0) << 6;  m |= (n1.w != 0) << 7;
    m |= (n2.x != 0) << 8;  m |= (n2.y != 0) << 9;  m |= (n2.z != 0) << 10; m |= (n2.w != 0) << 11;
    m |= (n3.x != 0) << 12; m |= (n3.y != 0) << 13; m |= (n3.z != 0) << 14; m |= (n3.w != 0) << 15;
    nb[(size_t)row * 256 + t] = (ushort)m;
}

// --- MFMA split-bf16 selection: 128x128 tile, 2x2 waves, rt=ct=4 ---
// A fragments direct from global (L2-resident); only B staged in LDS.
__global__ __launch_bounds__(256, 3)
void k_select(const ushort* __restrict__ ehi, const ushort* __restrict__ elo,
              const float* __restrict__ sq, const float* __restrict__ s,
              const int* __restrict__ inv,
              const ull* __restrict__ pbits, const ull* __restrict__ nbits,
              ull* __restrict__ pkey, ull* __restrict__ nkey) {
    __shared__ __align__(16) char smem[36864];   // Bh[128][72], Bl at +18432; scratch aliases
    __shared__ ull pbl[256], nbl[256];           // [row][2] 128-bit mask tile
    __shared__ float rjl[128];
    __shared__ int jvs[128];

    ushort* Bh = (ushort*)smem;
    ushort* Bl = (ushort*)(smem + 18432);

    const int tid = threadIdx.x;
    const int lane = tid & 63;
    const int w = tid >> 6, wr = w >> 1, wc = w & 1;
    const int lrow = lane & 15, quad = lane >> 4;
    const int i0 = blockIdx.x * 128, c0 = blockIdx.y * 128;

    if (tid < 128) {
        int j = inv[c0 + tid];
        jvs[tid] = j;
        rjl[tid] = sq[j] - 2.0f * EPSF * s[j];
    }
    {
        int r = tid >> 1, h = tid & 1;
        size_t b = (size_t)(i0 + r) * 64 + (c0 >> 6) + h;
        pbl[tid] = pbits[b];
        nbl[tid] = nbits[b];
    }
    __syncthreads();

    size_t aoff[4];
    #pragma unroll
    for (int rt = 0; rt < 4; rt++)
        aoff[rt] = (size_t)(i0 + wr * 64 + rt * 16 + lrow) * DD + quad * 8;

    f32x4 acc[4][4];
    #pragma unroll
    for (int rt = 0; rt < 4; rt++)
        #pragma unroll
        for (int ct = 0; ct < 4; ct++)
            acc[rt][ct] = (f32x4){0.f, 0.f, 0.f, 0.f};

    for (int kc = 0; kc < 2; kc++) {
        if (kc) __syncthreads();   // previous chunk's frag reads done
        // stage B chunk: rows jvs[0..127], k in [kc*64, kc*64+64)
        #pragma unroll
        for (int it = 0; it < 8; it++) {
            int slot = it * 256 + tid;
            int seg = slot & 7;
            int r = (slot >> 3) & 127;
            int jr = jvs[r];
            const ushort* src = (it < 4) ? ehi : elo;
            int4 v = ((const int4*)(src + (size_t)jr * DD))[kc * 8 + seg];
            ushort* dst = ((it < 4) ? Bh : Bl) + r * 72 + seg * 8;
            *(int4*)dst = v;
        }
        __syncthreads();
        #pragma unroll
        for (int ks = 0; ks < 2; ks++) {
            const int kof = kc * 64 + ks * 32;
            short8 ah[4], al[4];
            #pragma unroll
            for (int rt = 0; rt < 4; rt++) {
                ah[rt] = *(const short8*)(ehi + aoff[rt] + kof);
                al[rt] = *(const short8*)(elo + aoff[rt] + kof);
            }
            #pragma unroll
            for (int ct = 0; ct < 4; ct++) {
                const int bo = (wc * 64 + ct * 16 + lrow) * 72 + ks * 32 + quad * 8;
                short8 bh = *(const short8*)(Bh + bo);
                short8 bl = *(const short8*)(Bl + bo);
                #pragma unroll
                for (int rt = 0; rt < 4; rt++) {
                    acc[rt][ct] = __builtin_amdgcn_mfma_f32_16x16x32_bf16(ah[rt], bh, acc[rt][ct], 0, 0, 0);
                    acc[rt][ct] = __builtin_amdgcn_mfma_f32_16x16x32_bf16(ah[rt], bl, acc[rt][ct], 0, 0, 0);
                    acc[rt][ct] = __builtin_amdgcn_mfma_f32_16x16x32_bf16(al[rt], bh, acc[rt][ct], 0, 0, 0);
                }
            }
        }
    }

    // selection on m = rj - 2*dot (row-constant terms dropped; ordering per row identical)
    int jcol[4]; float rjc[4];
    #pragma unroll
    for (int ct = 0; ct < 4; ct++) {
        jcol[ct] = jvs[wc * 64 + ct * 16 + lrow];
        rjc[ct] = rjl[wc * 64 + ct * 16 + lrow];
    }
    float bpv[16], bnv[16]; int bpi[16], bni[16];
    #pragma unroll
    for (int k = 0; k < 16; k++) {
        bpv[k] = -3.4e38f; bnv[k] = 3.4e38f;
        bpi[k] = 0x7FFFFFFF; bni[k] = 0x7FFFFFFF;
    }
    #pragma unroll
    for (int rt = 0; rt < 4; rt++)
        #pragma unroll
        for (int t = 0; t < 4; t++) {
            const int slot = rt * 4 + t;
            const int row = wr * 64 + rt * 16 + quad * 4 + t;
            ull pb = pbl[row * 2 + wc] >> lrow;
            ull nb = nbl[row * 2 + wc] >> lrow;
            #pragma unroll
            for (int ct = 0; ct < 4; ct++) {
                float m = rjc[ct] - 2.0f * acc[rt][ct][t];
                int j = jcol[ct];
                if ((pb >> (ct * 16)) & 1ULL) {
                    if (m > bpv[slot] || (m == bpv[slot] && j < bpi[slot])) { bpv[slot] = m; bpi[slot] = j; }
                }
                if ((nb >> (ct * 16)) & 1ULL) {
                    if (m < bnv[slot] || (m == bnv[slot] && j < bni[slot])) { bnv[slot] = m; bni[slot] = j; }
                }
            }
        }

    // fold to packed keys; scratch aliases B staging (reads all done)
    __syncthreads();
    ull* scrp = (ull*)smem;               // [128][16]
    ull* scrn = (ull*)(smem + 16384);     // [128][16]
    #pragma unroll
    for (int rt = 0; rt < 4; rt++)
        #pragma unroll
        for (int t = 0; t < 4; t++) {
            const int slot = rt * 4 + t;
            const int row = wr * 64 + rt * 16 + quad * 4 + t;
            ull kp = (bpi[slot] == 0x7FFFFFFF) ? 0ULL
                   : (((ull)ord_f32(bpv[slot]) << 32) | (ull)(0xFFFFFFFFu - (unsigned)bpi[slot]));
            ull kn = (bni[slot] == 0x7FFFFFFF) ? 0ULL
                   : (((ull)(~ord_f32(bnv[slot])) << 32) | (ull)(0xFFFFFFFFu - (unsigned)bni[slot]));
            ull op = __shfl_xor(kp, 8); if (op > kp) kp = op;   // merge lrow / lrow^8 (same row, diff cols)
            ull on = __shfl_xor(kn, 8); if (on > kn) kn = on;
            if (lrow < 8) {
                scrp[row * 16 + wc * 8 + lrow] = kp;
                scrn[row * 16 + wc * 8 + lrow] = kn;
            }
        }
    __syncthreads();
    if (tid < 128) {
        ull kp = 0ULL, kn = 0ULL;
        for (int k = 0; k < 16; k++) {
            ull v = scrp[tid * 16 + k]; if (v > kp) kp = v;
            v = scrn[tid * 16 + k];     if (v > kn) kn = v;
        }
        if (kp) atomicMax(&pkey[i0 + tid], kp);
        if (kn) atomicMax(&nkey[i0 + tid], kn);
    }
}

// --- per-row triplet loss: wave per row (coalesced), block partials ---
__global__ void k_loss(const float* __restrict__ e,
                       const ull* __restrict__ pkey, const ull* __restrict__ nkey,
                       float* __restrict__ partials) {
    int w = threadIdx.x >> 6, lane = threadIdx.x & 63;
    int row = blockIdx.x * 4 + w;
    ull pk = pkey[row], nk = nkey[row];
    float loss = 0.0f, wt = 0.0f;
    if (pk != 0ULL && nk != 0ULL) {
        int pi = (int)(0xFFFFFFFFu - (unsigned)(pk & 0xFFFFFFFFu));
        int ni = (int)(0xFFFFFFFFu - (unsigned)(nk & 0xFFFFFFFFu));
        float2 av = ((const float2*)(e + (size_t)row * DD))[lane];
        float2 pv = ((const float2*)(e + (size_t)pi * DD))[lane];
        float2 nv = ((const float2*)(e + (size_t)ni * DD))[lane];
        float dx, dy;
        dx = av.x - pv.x + EPSF; dy = av.y - pv.y + EPSF;
        float ap2 = dx * dx + dy * dy;
        dx = av.x - nv.x + EPSF; dy = av.y - nv.y + EPSF;
        float an2 = dx * dx + dy * dy;
        dx = pv.x - nv.x + EPSF; dy = pv.y - nv.y + EPSF;
        float pn2 = dx * dx + dy * dy;
        #pragma unroll
        for (int off = 32; off > 0; off >>= 1) {
            ap2 += __shfl_down(ap2, off);
            an2 += __shfl_down(an2, off);
            pn2 += __shfl_down(pn2, off);
        }
        if (lane == 0) {
            float ap = sqrtf(ap2), an = sqrtf(an2), pn = sqrtf(pn2);
            loss = fmaxf(ap - fminf(an, pn) + MARGINF, 0.0f);
            wt = 1.0f;
        }
    }
    __shared__ float sl[4], sw[4];
    if (lane == 0) { sl[w] = loss; sw[w] = wt; }
    __syncthreads();
    if (threadIdx.x == 0) {
        partials[blockIdx.x * 2 + 0] = sl[0] + sl[1] + sl[2] + sl[3];
        partials[blockIdx.x * 2 + 1] = sw[0] + sw[1] + sw[2] + sw[3];
    }
}

// --- finalize ---
__global__ void k_final(const float* __restrict__ partials, float* __restrict__ out) {
    int tid = threadIdx.x;
    float L = 0.0f, W = 0.0f;
    for (int i = 0; i < 4; i++) {
        int idx = tid + i * 256;
        L += partials[idx * 2];
        W += partials[idx * 2 + 1];
    }
    #pragma unroll
    for (int off = 32; off > 0; off >>= 1) {
        L += __shfl_down(L, off);
        W += __shfl_down(W, off);
    }
    __shared__ float sl[4], sw[4];
    int w = tid >> 6, lane = tid & 63;
    if (lane == 0) { sl[w] = L; sw[w] = W; }
    __syncthreads();
    if (tid == 0) {
        float Lt = sl[0] + sl[1] + sl[2] + sl[3];
        float Wt = sw[0] + sw[1] + sw[2] + sw[3];
        out[0] = Lt / fmaxf(Wt, 1.0f);
    }
}

extern "C" void kernel_launch(void* const* d_in, const int* in_sizes, int n_in,
                              void* d_out, int out_size, void* d_ws, size_t ws_size,
                              hipStream_t stream) {
    const float* e    = (const float*)d_in[0];
    const int*   tidx = (const int*)d_in[1];
    const int*   pos  = (const int*)d_in[2];
    const int*   neg  = (const int*)d_in[3];
    float* out = (float*)d_out;

    ull* pkey  = (ull*)d_ws;                  // 4096
    ull* nkey  = pkey + BN;                   // 4096
    ull* pbits = nkey + BN;                   // 4096*64
    ull* nbits = pbits + BN * 64;             // 4096*64
    float* sq  = (float*)(nbits + BN * 64);
    float* s   = sq + BN;
    int* inv   = (int*)(s + BN);
    float* partials = (float*)(inv + BN);     // 2048
    unsigned int* ehi = (unsigned int*)(partials + 2048);  // 4096*64 uints
    unsigned int* elo = ehi + BN * 64;

    k_prep<<<BN / 4, 256, 0, stream>>>(e, tidx, sq, s, inv, pkey, nkey, ehi, elo);
    k_bits<<<BN, 256, 0, stream>>>(pos, neg, (ushort*)pbits, (ushort*)nbits);
    dim3 grid(BN / 128, BN / 128);
    k_select<<<grid, 256, 0, stream>>>((const ushort*)ehi, (const ushort*)elo,
                                       sq, s, inv, pbits, nbits, pkey, nkey);
    k_loss<<<BN / 4, 256, 0, stream>>>(e, pkey, nkey, partials);
    k_final<<<1, 256, 0, stream>>>(partials, out);
}

// Round 8
// 185.661 us; speedup vs baseline: 1.3363x; 1.0946x over previous
//
#include <hip/hip_runtime.h>
#include <stdint.h>

#define BN 4096
#define DD 128
#define EPSF 1e-6f
#define MARGINF 1.0f

typedef unsigned long long ull;
typedef unsigned short ushort;
typedef short short8 __attribute__((ext_vector_type(8)));
typedef float f32x4 __attribute__((ext_vector_type(4)));

__device__ __forceinline__ unsigned int ord_f32(float f) {
    unsigned int u = __float_as_uint(f);
    return (u & 0x80000000u) ? ~u : (u | 0x80000000u);
}
__device__ __forceinline__ ushort bf16_rne(float x) {
    unsigned int u = __float_as_uint(x);
    return (ushort)((u + 0x7FFFu + ((u >> 16) & 1u)) >> 16);
}

// --- prep: row stats + inv perm + key init + bf16 convert of e ---
__global__ void k_prep(const float* __restrict__ e, const int* __restrict__ tidx,
                       float* __restrict__ sq, float* __restrict__ s,
                       int* __restrict__ inv, ull* __restrict__ pk, ull* __restrict__ nk,
                       unsigned int* __restrict__ ehi) {
    int w = threadIdx.x >> 6, lane = threadIdx.x & 63;
    int row = blockIdx.x * 4 + w;
    float2 v = ((const float2*)(e + (size_t)row * DD))[lane];
    ushort hx = bf16_rne(v.x), hy = bf16_rne(v.y);
    ehi[row * 64 + lane] = (unsigned int)hx | ((unsigned int)hy << 16);
    float ss = v.x + v.y;
    float qq = v.x * v.x + v.y * v.y;
    #pragma unroll
    for (int off = 32; off > 0; off >>= 1) {
        ss += __shfl_down(ss, off);
        qq += __shfl_down(qq, off);
    }
    if (lane == 0) {
        sq[row] = qq; s[row] = ss;
        inv[tidx[row]] = row;
        pk[row] = 0ULL; nk[row] = 0ULL;   // both max-merged (neg uses inverted keys)
    }
}

// --- compress masks to bitmaps: thread = 16 consecutive cols, no ballot ---
__global__ void k_bits(const int* __restrict__ pos, const int* __restrict__ neg,
                       ushort* __restrict__ pb, ushort* __restrict__ nb) {
    const int row = blockIdx.x, t = threadIdx.x;
    const int4* pr = (const int4*)(pos + (size_t)row * BN) + t * 4;
    const int4* nr = (const int4*)(neg + (size_t)row * BN) + t * 4;
    int4 p0 = pr[0], p1 = pr[1], p2 = pr[2], p3 = pr[3];
    int4 n0 = nr[0], n1 = nr[1], n2 = nr[2], n3 = nr[3];
    unsigned int m = 0;
    m |= (p0.x != 0) << 0;  m |= (p0.y != 0) << 1;  m |= (p0.z != 0) << 2;  m |= (p0.w != 0) << 3;
    m |= (p1.x != 0) << 4;  m |= (p1.y != 0) << 5;  m |= (p1.z != 0) << 6;  m |= (p1.w != 0) << 7;
    m |= (p2.x != 0) << 8;  m |= (p2.y != 0) << 9;  m |= (p2.z != 0) << 10; m |= (p2.w != 0) << 11;
    m |= (p3.x != 0) << 12; m |= (p3.y != 0) << 13; m |= (p3.z != 0) << 14; m |= (p3.w != 0) << 15;
    pb[(size_t)row * 256 + t] = (ushort)m;
    m = 0;
    m |= (n0.x != 0) << 0;  m |= (n0.y != 0) << 1;  m |= (n0.z != 0) << 2;  m |= (n0.w != 0) << 3;
    m |= (n1.x != 0) << 4;  m |= (n1.y != 0) << 5;  m |= (n1.z != 0) << 6;  m |= (n1.w != 0) << 7;
    m |= (n2.x != 0) << 8;  m |= (n2.y != 0) << 9;  m |= (n2.z != 0) << 10; m |= (n2.w != 0) << 11;
    m |= (n3.x != 0) << 12; m |= (n3.y != 0) << 13; m |= (n3.z != 0) << 14; m |= (n3.w != 0) << 15;
    nb[(size_t)row * 256 + t] = (ushort)m;
}

// --- single-pass bf16 MFMA selection: 128x128 tile, B staged once for all K ---
__global__ __launch_bounds__(256, 4)
void k_select(const ushort* __restrict__ ehi,
              const float* __restrict__ sq, const float* __restrict__ s,
              const int* __restrict__ inv,
              const ull* __restrict__ pbits, const ull* __restrict__ nbits,
              ull* __restrict__ pkey, ull* __restrict__ nkey) {
    // B staging [2 kc][128 r][72 pad] ushorts = 36 KB; later aliased:
    //   [0,2K) pbl, [2K,4K) nbl, [4K,20K) scrp[16][128], [20K,36K) scrn[16][128]
    __shared__ __align__(16) char smem[36864];
    __shared__ float rjl[128];
    __shared__ int jvs[128];

    ushort* Bst = (ushort*)smem;

    const int tid = threadIdx.x;
    const int lane = tid & 63;
    const int w = tid >> 6, wr = w >> 1, wc = w & 1;
    const int lrow = lane & 15, quad = lane >> 4;
    const int i0 = blockIdx.x * 128, c0 = blockIdx.y * 128;

    if (tid < 128) {
        int j = inv[c0 + tid];
        jvs[tid] = j;
        rjl[tid] = sq[j] - 2.0f * EPSF * s[j];
    }
    __syncthreads();

    // stage B: 128 gathered rows x 256 B, once for all K
    #pragma unroll
    for (int it = 0; it < 8; it++) {
        int slot = it * 256 + tid;
        int r = slot >> 4, seg16 = slot & 15;
        int kc = seg16 >> 3, seg = seg16 & 7;
        int jr = jvs[r];
        int4 v = ((const int4*)ehi)[(size_t)jr * 16 + seg16];
        *(int4*)(Bst + (kc * 128 + r) * 72 + seg * 8) = v;
    }
    __syncthreads();

    f32x4 acc[4][4];
    #pragma unroll
    for (int rt = 0; rt < 4; rt++)
        #pragma unroll
        for (int ct = 0; ct < 4; ct++)
            acc[rt][ct] = (f32x4){0.f, 0.f, 0.f, 0.f};

    size_t abase[4];
    #pragma unroll
    for (int rt = 0; rt < 4; rt++)
        abase[rt] = (size_t)(i0 + wr * 64 + rt * 16 + lrow) * DD + quad * 8;

    // K-loop: no barriers; A direct from global (L2-resident), B from LDS
    #pragma unroll
    for (int ks = 0; ks < 4; ks++) {
        const int kc = ks >> 1, ksl = ks & 1;
        short8 ah[4];
        #pragma unroll
        for (int rt = 0; rt < 4; rt++)
            ah[rt] = *(const short8*)(ehi + abase[rt] + ks * 32);
        #pragma unroll
        for (int ct = 0; ct < 4; ct++) {
            const int bo = (kc * 128 + wc * 64 + ct * 16 + lrow) * 72 + ksl * 32 + quad * 8;
            short8 bh = *(const short8*)(Bst + bo);
            #pragma unroll
            for (int rt = 0; rt < 4; rt++)
                acc[rt][ct] = __builtin_amdgcn_mfma_f32_16x16x32_bf16(ah[rt], bh, acc[rt][ct], 0, 0, 0);
        }
    }

    __syncthreads();   // B reads done; alias region now safe
    ull* pbl = (ull*)smem;                  // [128][2]
    ull* nbl = (ull*)(smem + 2048);
    {
        int r = tid >> 1, h = tid & 1;
        size_t b = (size_t)(i0 + r) * 64 + (c0 >> 6) + h;
        pbl[tid] = pbits[b];
        nbl[tid] = nbits[b];
    }
    __syncthreads();

    // selection on m = rj - 2*dot (row-constant terms dropped; per-row order identical)
    int jcol[4]; float rjc[4];
    #pragma unroll
    for (int ct = 0; ct < 4; ct++) {
        jcol[ct] = jvs[wc * 64 + ct * 16 + lrow];
        rjc[ct] = rjl[wc * 64 + ct * 16 + lrow];
    }
    ull* scrp = (ull*)(smem + 4096);        // [16][128]
    ull* scrn = (ull*)(smem + 20480);       // [16][128]
    #pragma unroll
    for (int rt = 0; rt < 4; rt++)
        #pragma unroll
        for (int t = 0; t < 4; t++) {
            const int row = wr * 64 + rt * 16 + quad * 4 + t;
            ull pb = pbl[row * 2 + wc] >> lrow;
            ull nb = nbl[row * 2 + wc] >> lrow;
            float bpv = -3.4e38f, bnv = 3.4e38f;
            int bpi = 0x7FFFFFFF, bni = 0x7FFFFFFF;
            #pragma unroll
            for (int ct = 0; ct < 4; ct++) {
                float m = rjc[ct] - 2.0f * acc[rt][ct][t];
                int j = jcol[ct];
                if ((pb >> (ct * 16)) & 1ULL) {
                    if (m > bpv || (m == bpv && j < bpi)) { bpv = m; bpi = j; }
                }
                if ((nb >> (ct * 16)) & 1ULL) {
                    if (m < bnv || (m == bnv && j < bni)) { bnv = m; bni = j; }
                }
            }
            ull kp = (bpi == 0x7FFFFFFF) ? 0ULL
                   : (((ull)ord_f32(bpv) << 32) | (ull)(0xFFFFFFFFu - (unsigned)bpi));
            ull kn = (bni == 0x7FFFFFFF) ? 0ULL
                   : (((ull)(~ord_f32(bnv)) << 32) | (ull)(0xFFFFFFFFu - (unsigned)bni));
            ull op = __shfl_xor(kp, 8); if (op > kp) kp = op;   // fold lrow with lrow^8
            ull on = __shfl_xor(kn, 8); if (on > kn) kn = on;
            if (lrow < 8) {
                scrp[(wc * 8 + lrow) * 128 + row] = kp;   // [k][row]: conflict-free read
                scrn[(wc * 8 + lrow) * 128 + row] = kn;
            }
        }
    __syncthreads();
    if (tid < 128) {
        ull kp = 0ULL, kn = 0ULL;
        #pragma unroll
        for (int k = 0; k < 16; k++) {
            ull v = scrp[k * 128 + tid]; if (v > kp) kp = v;
            v = scrn[k * 128 + tid];     if (v > kn) kn = v;
        }
        if (kp) atomicMax(&pkey[i0 + tid], kp);
        if (kn) atomicMax(&nkey[i0 + tid], kn);
    }
}

// --- per-row triplet loss: wave per row (coalesced), block partials ---
__global__ void k_loss(const float* __restrict__ e,
                       const ull* __restrict__ pkey, const ull* __restrict__ nkey,
                       float* __restrict__ partials) {
    int w = threadIdx.x >> 6, lane = threadIdx.x & 63;
    int row = blockIdx.x * 4 + w;
    ull pk = pkey[row], nk = nkey[row];
    float loss = 0.0f, wt = 0.0f;
    if (pk != 0ULL && nk != 0ULL) {
        int pi = (int)(0xFFFFFFFFu - (unsigned)(pk & 0xFFFFFFFFu));
        int ni = (int)(0xFFFFFFFFu - (unsigned)(nk & 0xFFFFFFFFu));
        float2 av = ((const float2*)(e + (size_t)row * DD))[lane];
        float2 pv = ((const float2*)(e + (size_t)pi * DD))[lane];
        float2 nv = ((const float2*)(e + (size_t)ni * DD))[lane];
        float dx, dy;
        dx = av.x - pv.x + EPSF; dy = av.y - pv.y + EPSF;
        float ap2 = dx * dx + dy * dy;
        dx = av.x - nv.x + EPSF; dy = av.y - nv.y + EPSF;
        float an2 = dx * dx + dy * dy;
        dx = pv.x - nv.x + EPSF; dy = pv.y - nv.y + EPSF;
        float pn2 = dx * dx + dy * dy;
        #pragma unroll
        for (int off = 32; off > 0; off >>= 1) {
            ap2 += __shfl_down(ap2, off);
            an2 += __shfl_down(an2, off);
            pn2 += __shfl_down(pn2, off);
        }
        if (lane == 0) {
            float ap = sqrtf(ap2), an = sqrtf(an2), pn = sqrtf(pn2);
            loss = fmaxf(ap - fminf(an, pn) + MARGINF, 0.0f);
            wt = 1.0f;
        }
    }
    __shared__ float sl[4], sw[4];
    if (lane == 0) { sl[w] = loss; sw[w] = wt; }
    __syncthreads();
    if (threadIdx.x == 0) {
        partials[blockIdx.x * 2 + 0] = sl[0] + sl[1] + sl[2] + sl[3];
        partials[blockIdx.x * 2 + 1] = sw[0] + sw[1] + sw[2] + sw[3];
    }
}

// --- finalize ---
__global__ void k_final(const float* __restrict__ partials, float* __restrict__ out) {
    int tid = threadIdx.x;
    float L = 0.0f, W = 0.0f;
    for (int i = 0; i < 4; i++) {
        int idx = tid + i * 256;
        L += partials[idx * 2];
        W += partials[idx * 2 + 1];
    }
    #pragma unroll
    for (int off = 32; off > 0; off >>= 1) {
        L += __shfl_down(L, off);
        W += __shfl_down(W, off);
    }
    __shared__ float sl[4], sw[4];
    int w = tid >> 6, lane = tid & 63;
    if (lane == 0) { sl[w] = L; sw[w] = W; }
    __syncthreads();
    if (tid == 0) {
        float Lt = sl[0] + sl[1] + sl[2] + sl[3];
        float Wt = sw[0] + sw[1] + sw[2] + sw[3];
        out[0] = Lt / fmaxf(Wt, 1.0f);
    }
}

extern "C" void kernel_launch(void* const* d_in, const int* in_sizes, int n_in,
                              void* d_out, int out_size, void* d_ws, size_t ws_size,
                              hipStream_t stream) {
    const float* e    = (const float*)d_in[0];
    const int*   tidx = (const int*)d_in[1];
    const int*   pos  = (const int*)d_in[2];
    const int*   neg  = (const int*)d_in[3];
    float* out = (float*)d_out;

    ull* pkey  = (ull*)d_ws;                  // 4096
    ull* nkey  = pkey + BN;                   // 4096
    ull* pbits = nkey + BN;                   // 4096*64
    ull* nbits = pbits + BN * 64;             // 4096*64
    float* sq  = (float*)(nbits + BN * 64);
    float* s   = sq + BN;
    int* inv   = (int*)(s + BN);
    float* partials = (float*)(inv + BN);     // 2048
    unsigned int* ehi = (unsigned int*)(partials + 2048);  // 4096*64 uints

    k_prep<<<BN / 4, 256, 0, stream>>>(e, tidx, sq, s, inv, pkey, nkey, ehi);
    k_bits<<<BN, 256, 0, stream>>>(pos, neg, (ushort*)pbits, (ushort*)nbits);
    dim3 grid(BN / 128, BN / 128);
    k_select<<<grid, 256, 0, stream>>>((const ushort*)ehi, sq, s, inv,
                                       pbits, nbits, pkey, nkey);
    k_loss<<<BN / 4, 256, 0, stream>>>(e, pkey, nkey, partials);
    k_final<<<1, 256, 0, stream>>>(partials, out);
}

// Round 9
// 184.505 us; speedup vs baseline: 1.3447x; 1.0063x over previous
//
#include <hip/hip_runtime.h>
#include <stdint.h>

#define BN 4096
#define DD 128
#define EPSF 1e-6f
#define MARGINF 1.0f

typedef unsigned long long ull;
typedef unsigned short ushort;
typedef short short8 __attribute__((ext_vector_type(8)));
typedef float f32x4 __attribute__((ext_vector_type(4)));

__device__ __forceinline__ unsigned int ord_f32(float f) {
    unsigned int u = __float_as_uint(f);
    return (u & 0x80000000u) ? ~u : (u | 0x80000000u);
}
__device__ __forceinline__ ushort bf16_rne(float x) {
    unsigned int u = __float_as_uint(x);
    return (ushort)((u + 0x7FFFu + ((u >> 16) & 1u)) >> 16);
}
// 8 bytes (low nibbles valid) -> 32-bit packed nibbles
__device__ __forceinline__ unsigned int pack8(ull v) {
    v &= 0x0F0F0F0F0F0F0F0FULL;
    v = (v | (v >> 4)) & 0x00FF00FF00FF00FFULL;
    v = (v | (v >> 8)) & 0x0000FFFF0000FFFFULL;
    v = (v | (v >> 16));
    return (unsigned int)v;
}

// --- prep: row stats + inv perm + key init + bf16 convert of e ---
__global__ void k_prep(const float* __restrict__ e, const int* __restrict__ tidx,
                       float* __restrict__ sq, float* __restrict__ s,
                       int* __restrict__ inv, ull* __restrict__ pk, ull* __restrict__ nk,
                       unsigned int* __restrict__ ehi) {
    int w = threadIdx.x >> 6, lane = threadIdx.x & 63;
    int row = blockIdx.x * 4 + w;
    float2 v = ((const float2*)(e + (size_t)row * DD))[lane];
    ushort hx = bf16_rne(v.x), hy = bf16_rne(v.y);
    ehi[row * 64 + lane] = (unsigned int)hx | ((unsigned int)hy << 16);
    float ss = v.x + v.y;
    float qq = v.x * v.x + v.y * v.y;
    #pragma unroll
    for (int off = 32; off > 0; off >>= 1) {
        ss += __shfl_down(ss, off);
        qq += __shfl_down(qq, off);
    }
    if (lane == 0) {
        sq[row] = qq; s[row] = ss;
        inv[tidx[row]] = row;
        pk[row] = 0ULL; nk[row] = 0ULL;   // both max-merged (neg uses inverted keys)
    }
}

// --- fused: mask tile compress + bf16 MFMA + selection; 128x128 tile ---
__global__ __launch_bounds__(256, 4)
void k_select(const ushort* __restrict__ ehi,
              const int* __restrict__ pos, const int* __restrict__ neg,
              const float* __restrict__ sq, const float* __restrict__ s,
              const int* __restrict__ inv,
              ull* __restrict__ pkey, ull* __restrict__ nkey) {
    // smem phases:
    //  phase1: [0,4K) nibP[128][32], [4K,8K) nibN[128][32]
    //  phase2: B staging [2 kc][128 r][72] ushorts = 36 KB
    //  phase3: [0,2K) pbl[256], [2K,4K) nbl[256], [4K,20K) scrp, [20K,36K) scrn
    __shared__ __align__(16) char smem[36864];
    __shared__ float rjl[128];
    __shared__ int jvs[128];

    const int tid = threadIdx.x;
    const int lane = tid & 63;
    const int w = tid >> 6, wr = w >> 1, wc = w & 1;
    const int lrow = lane & 15, quad = lane >> 4;
    const int i0 = blockIdx.x * 128, c0 = blockIdx.y * 128;

    if (tid < 128) {
        int j = inv[c0 + tid];
        jvs[tid] = j;
        rjl[tid] = sq[j] - 2.0f * EPSF * s[j];
    }

    // phase 1: coalesced mask tile loads -> nibbles in LDS
    unsigned char* nibP = (unsigned char*)smem;
    unsigned char* nibN = (unsigned char*)(smem + 4096);
    {
        const int4* pbase = (const int4*)(pos + (size_t)i0 * BN + c0);
        const int4* nbase = (const int4*)(neg + (size_t)i0 * BN + c0);
        #pragma unroll
        for (int p = 0; p < 16; p++) {
            int flat = p * 256 + tid;
            int r = flat >> 5, q = flat & 31;        // row r, int4-index q (4 cols)
            size_t idx = (size_t)r * (BN / 4) + q;
            int4 P = pbase[idx];
            int4 N = nbase[idx];
            unsigned int pm = (unsigned int)(P.x != 0) | ((unsigned int)(P.y != 0) << 1)
                            | ((unsigned int)(P.z != 0) << 2) | ((unsigned int)(P.w != 0) << 3);
            unsigned int nm = (unsigned int)(N.x != 0) | ((unsigned int)(N.y != 0) << 1)
                            | ((unsigned int)(N.z != 0) << 2) | ((unsigned int)(N.w != 0) << 3);
            nibP[r * 32 + q] = (unsigned char)pm;
            nibN[r * 32 + q] = (unsigned char)nm;
        }
    }
    __syncthreads();

    // pack this thread's (row = tid>>1, half = tid&1) 64-bit mask words into regs
    ull pw, nw;
    {
        int off = (tid >> 1) * 32 + (tid & 1) * 16;
        ull lo = *(const ull*)(nibP + off);
        ull hi = *(const ull*)(nibP + off + 8);
        pw = (ull)pack8(lo) | ((ull)pack8(hi) << 32);
        lo = *(const ull*)(nibN + off);
        hi = *(const ull*)(nibN + off + 8);
        nw = (ull)pack8(lo) | ((ull)pack8(hi) << 32);
    }
    __syncthreads();   // nib reads done; jvs visible; B staging may overwrite

    // phase 2: stage B (gathered rows) once for all K
    ushort* Bst = (ushort*)smem;
    #pragma unroll
    for (int it = 0; it < 8; it++) {
        int slot = it * 256 + tid;
        int r = slot >> 4, seg16 = slot & 15;
        int kc = seg16 >> 3, seg = seg16 & 7;
        int jr = jvs[r];
        int4 v = ((const int4*)ehi)[(size_t)jr * 16 + seg16];
        *(int4*)(Bst + (kc * 128 + r) * 72 + seg * 8) = v;
    }
    __syncthreads();

    f32x4 acc[4][4];
    #pragma unroll
    for (int rt = 0; rt < 4; rt++)
        #pragma unroll
        for (int ct = 0; ct < 4; ct++)
            acc[rt][ct] = (f32x4){0.f, 0.f, 0.f, 0.f};

    size_t abase[4];
    #pragma unroll
    for (int rt = 0; rt < 4; rt++)
        abase[rt] = (size_t)(i0 + wr * 64 + rt * 16 + lrow) * DD + quad * 8;

    // K-loop: no barriers; A direct from global (L2-resident), B from LDS
    #pragma unroll
    for (int ks = 0; ks < 4; ks++) {
        const int kc = ks >> 1, ksl = ks & 1;
        short8 ah[4];
        #pragma unroll
        for (int rt = 0; rt < 4; rt++)
            ah[rt] = *(const short8*)(ehi + abase[rt] + ks * 32);
        #pragma unroll
        for (int ct = 0; ct < 4; ct++) {
            const int bo = (kc * 128 + wc * 64 + ct * 16 + lrow) * 72 + ksl * 32 + quad * 8;
            short8 bh = *(const short8*)(Bst + bo);
            #pragma unroll
            for (int rt = 0; rt < 4; rt++)
                acc[rt][ct] = __builtin_amdgcn_mfma_f32_16x16x32_bf16(ah[rt], bh, acc[rt][ct], 0, 0, 0);
        }
    }

    __syncthreads();   // B reads done; alias region now safe
    ull* pbl = (ull*)smem;                  // [128][2]
    ull* nbl = (ull*)(smem + 2048);
    pbl[tid] = pw;
    nbl[tid] = nw;
    __syncthreads();

    // selection on m = rj - 2*dot (row-constant terms dropped; per-row order identical)
    int jcol[4]; float rjc[4];
    #pragma unroll
    for (int ct = 0; ct < 4; ct++) {
        jcol[ct] = jvs[wc * 64 + ct * 16 + lrow];
        rjc[ct] = rjl[wc * 64 + ct * 16 + lrow];
    }
    ull* scrp = (ull*)(smem + 4096);        // [16][128]
    ull* scrn = (ull*)(smem + 20480);       // [16][128]
    #pragma unroll
    for (int rt = 0; rt < 4; rt++)
        #pragma unroll
        for (int t = 0; t < 4; t++) {
            const int row = wr * 64 + rt * 16 + quad * 4 + t;
            ull pb = pbl[row * 2 + wc] >> lrow;
            ull nb = nbl[row * 2 + wc] >> lrow;
            float bpv = -3.4e38f, bnv = 3.4e38f;
            int bpi = 0x7FFFFFFF, bni = 0x7FFFFFFF;
            #pragma unroll
            for (int ct = 0; ct < 4; ct++) {
                float m = rjc[ct] - 2.0f * acc[rt][ct][t];
                int j = jcol[ct];
                if ((pb >> (ct * 16)) & 1ULL) {
                    if (m > bpv || (m == bpv && j < bpi)) { bpv = m; bpi = j; }
                }
                if ((nb >> (ct * 16)) & 1ULL) {
                    if (m < bnv || (m == bnv && j < bni)) { bnv = m; bni = j; }
                }
            }
            ull kp = (bpi == 0x7FFFFFFF) ? 0ULL
                   : (((ull)ord_f32(bpv) << 32) | (ull)(0xFFFFFFFFu - (unsigned)bpi));
            ull kn = (bni == 0x7FFFFFFF) ? 0ULL
                   : (((ull)(~ord_f32(bnv)) << 32) | (ull)(0xFFFFFFFFu - (unsigned)bni));
            ull op = __shfl_xor(kp, 8); if (op > kp) kp = op;   // fold lrow with lrow^8
            ull on = __shfl_xor(kn, 8); if (on > kn) kn = on;
            if (lrow < 8) {
                scrp[(wc * 8 + lrow) * 128 + row] = kp;   // [k][row]: conflict-free read
                scrn[(wc * 8 + lrow) * 128 + row] = kn;
            }
        }
    __syncthreads();
    if (tid < 128) {
        ull kp = 0ULL, kn = 0ULL;
        #pragma unroll
        for (int k = 0; k < 16; k++) {
            ull v = scrp[k * 128 + tid]; if (v > kp) kp = v;
            v = scrn[k * 128 + tid];     if (v > kn) kn = v;
        }
        if (kp) atomicMax(&pkey[i0 + tid], kp);
        if (kn) atomicMax(&nkey[i0 + tid], kn);
    }
}

// --- per-row triplet loss: wave per row (coalesced), block partials ---
__global__ void k_loss(const float* __restrict__ e,
                       const ull* __restrict__ pkey, const ull* __restrict__ nkey,
                       float* __restrict__ partials) {
    int w = threadIdx.x >> 6, lane = threadIdx.x & 63;
    int row = blockIdx.x * 4 + w;
    ull pk = pkey[row], nk = nkey[row];
    float loss = 0.0f, wt = 0.0f;
    if (pk != 0ULL && nk != 0ULL) {
        int pi = (int)(0xFFFFFFFFu - (unsigned)(pk & 0xFFFFFFFFu));
        int ni = (int)(0xFFFFFFFFu - (unsigned)(nk & 0xFFFFFFFFu));
        float2 av = ((const float2*)(e + (size_t)row * DD))[lane];
        float2 pv = ((const float2*)(e + (size_t)pi * DD))[lane];
        float2 nv = ((const float2*)(e + (size_t)ni * DD))[lane];
        float dx, dy;
        dx = av.x - pv.x + EPSF; dy = av.y - pv.y + EPSF;
        float ap2 = dx * dx + dy * dy;
        dx = av.x - nv.x + EPSF; dy = av.y - nv.y + EPSF;
        float an2 = dx * dx + dy * dy;
        dx = pv.x - nv.x + EPSF; dy = pv.y - nv.y + EPSF;
        float pn2 = dx * dx + dy * dy;
        #pragma unroll
        for (int off = 32; off > 0; off >>= 1) {
            ap2 += __shfl_down(ap2, off);
            an2 += __shfl_down(an2, off);
            pn2 += __shfl_down(pn2, off);
        }
        if (lane == 0) {
            float ap = sqrtf(ap2), an = sqrtf(an2), pn = sqrtf(pn2);
            loss = fmaxf(ap - fminf(an, pn) + MARGINF, 0.0f);
            wt = 1.0f;
        }
    }
    __shared__ float sl[4], sw[4];
    if (lane == 0) { sl[w] = loss; sw[w] = wt; }
    __syncthreads();
    if (threadIdx.x == 0) {
        partials[blockIdx.x * 2 + 0] = sl[0] + sl[1] + sl[2] + sl[3];
        partials[blockIdx.x * 2 + 1] = sw[0] + sw[1] + sw[2] + sw[3];
    }
}

// --- finalize ---
__global__ void k_final(const float* __restrict__ partials, float* __restrict__ out) {
    int tid = threadIdx.x;
    float L = 0.0f, W = 0.0f;
    for (int i = 0; i < 4; i++) {
        int idx = tid + i * 256;
        L += partials[idx * 2];
        W += partials[idx * 2 + 1];
    }
    #pragma unroll
    for (int off = 32; off > 0; off >>= 1) {
        L += __shfl_down(L, off);
        W += __shfl_down(W, off);
    }
    __shared__ float sl[4], sw[4];
    int w = tid >> 6, lane = tid & 63;
    if (lane == 0) { sl[w] = L; sw[w] = W; }
    __syncthreads();
    if (tid == 0) {
        float Lt = sl[0] + sl[1] + sl[2] + sl[3];
        float Wt = sw[0] + sw[1] + sw[2] + sw[3];
        out[0] = Lt / fmaxf(Wt, 1.0f);
    }
}

extern "C" void kernel_launch(void* const* d_in, const int* in_sizes, int n_in,
                              void* d_out, int out_size, void* d_ws, size_t ws_size,
                              hipStream_t stream) {
    const float* e    = (const float*)d_in[0];
    const int*   tidx = (const int*)d_in[1];
    const int*   pos  = (const int*)d_in[2];
    const int*   neg  = (const int*)d_in[3];
    float* out = (float*)d_out;

    ull* pkey  = (ull*)d_ws;                  // 4096
    ull* nkey  = pkey + BN;                   // 4096
    float* sq  = (float*)(nkey + BN);
    float* s   = sq + BN;
    int* inv   = (int*)(s + BN);
    float* partials = (float*)(inv + BN);     // 2048
    unsigned int* ehi = (unsigned int*)(partials + 2048);  // 4096*64 uints

    k_prep<<<BN / 4, 256, 0, stream>>>(e, tidx, sq, s, inv, pkey, nkey, ehi);
    dim3 grid(BN / 128, BN / 128);
    k_select<<<grid, 256, 0, stream>>>((const ushort*)ehi, pos, neg,
                                       sq, s, inv, pkey, nkey);
    k_loss<<<BN / 4, 256, 0, stream>>>(e, pkey, nkey, partials);
    k_final<<<1, 256, 0, stream>>>(partials, out);
}